// Round 9
// baseline (810.573 us; speedup 1.0000x reference)
//
#include <hip/hip_runtime.h>

#define TT 4096
#define NB 512
#define NH 10
#define NL 8
#define KS 16          // timesteps per barrier interval
#define NTI (TT/KS)    // 256 t-intervals per layer
#define NI (NTI + NL - 1)

// ---- DPP lane exchange within each row of 16 lanes (VALU pipe, no LDS) ----
//   row_shr:N -> dst lane i gets src lane i-N ; row_shl:N -> lane i+N
__device__ __forceinline__ float dpp_xor1(float v) {   // quad_perm [1,0,3,2]
    return __int_as_float(__builtin_amdgcn_update_dpp(
        __float_as_int(v), __float_as_int(v), 0xB1, 0xF, 0xF, false));
}
__device__ __forceinline__ float dpp_xor2(float v) {   // quad_perm [2,3,0,1]
    return __int_as_float(__builtin_amdgcn_update_dpp(
        __float_as_int(v), __float_as_int(v), 0x4E, 0xF, 0xF, false));
}
__device__ __forceinline__ float dpp_xor4(float v) {
    // banks 0,2 (h&4==0) need lane h+4 -> row_shl:4 ; banks 1,3 need h-4 -> row_shr:4
    int t = __builtin_amdgcn_update_dpp(
        __float_as_int(v), __float_as_int(v), 0x104, 0xF, 0x5, false); // shl:4
    t = __builtin_amdgcn_update_dpp(
        t, __float_as_int(v), 0x114, 0xF, 0xA, false);                 // shr:4
    return __int_as_float(t);
}
// xor8 applied ONLY to rows 2,3 (lanes 32-63); rows 0,1 keep the old value.
__device__ __forceinline__ float dpp_xor8_hi(float v) {
    return __int_as_float(__builtin_amdgcn_update_dpp(
        __float_as_int(v), __float_as_int(v), 0x128, 0xC, 0xF, false)); // row_ror:8
}
// Sum of the two 32-lane halves, delivered to every lane:
// after swap, (a + b) = lo_partial + hi_partial in all 64 lanes.
__device__ __forceinline__ float half_sum(float z) {
    float a = z, bq = z;
    asm volatile("s_nop 1\n\tv_permlane32_swap_b32 %0, %1"
                 : "+v"(a), "+v"(bq));
    return a + bq;
}

// 8 waves/block (wave = layer), 2 batches/wave, each batch replicated across
// the two 32-lane halves; half m owns terms j in {8m..8m+7} of every 16-dot.
// Grid = 256 blocks -> every CU. Cross-layer handoff: producer writes its
// PARTIAL projection (one b32/step) to a pad-17 slab; the consumer's per-step
// permlane32 combine sums the halves. One barrier per KS steps.
__global__ __launch_bounds__(512, 1)
void rnn_pipe(const float* __restrict__ x, const float* __restrict__ h0,
              const float* __restrict__ w_ih0, const float* __restrict__ w_ih_rest,
              const float* __restrict__ w_hh, const float* __restrict__ b_ih,
              const float* __restrict__ b_hh, const float* __restrict__ w_lin,
              const float* __restrict__ b_lin, float* __restrict__ out)
{
    // [parity][producer_layer][lane][16 k's + pad]
    __shared__ float pbuf[2][NL-1][64][17];            // 60928 B

    const int tid  = threadIdx.x;
    const int wv   = tid >> 6;          // layer index
    const int lane = tid & 63;
    const int half = lane >> 5;         // which 8-term slice of the dots
    const int bg   = (lane >> 4) & 1;   // batch within wave
    const int h    = lane & 15;         // hidden unit (padded 10->16)
    const int b    = blockIdx.x * 2 + bg;
    const int off  = half << 3;

    const float SC = 2.8853900817779268f;   // 2*log2(e), folded into z

    // ---- per-lane weights, pre-permuted: X[j] is the coef of r[j]=th[h^j^off]
    float W[8];     // own recurrence whh (SC-folded)
    float WN[8];    // wv<7: consumer's wih (SC-folded); wv==7: w_lin
    float w0s = 0.f, bias2h = 0.f, bias2p = 0.f;
    const float blin = b_lin[0];

    #pragma unroll
    for (int j = 0; j < 8; ++j) {
        const int src = h ^ j ^ off;
        W[j] = (h < NH && src < NH) ? SC * w_hh[(wv*NH + h)*NH + src] : 0.f;
        if (wv < NL-1)   // layer wv+1's W_ih = w_ih_rest[wv]
            WN[j] = (h < NH && src < NH) ? SC * w_ih_rest[(wv*NH + h)*NH + src] : 0.f;
        else
            WN[j] = (src < NH) ? w_lin[src] : 0.f;
    }
    if (h < NH && half == 0) {          // bias/x terms live in half 0 only
        const float bb = SC * (b_ih[wv*NH + h] + b_hh[wv*NH + h]);
        if (wv == 0) { w0s = SC * w_ih0[h]; bias2p = bb; }
        else bias2h = bb;
    }

    // ---- state init: r[j] = h0 of unit h^j^off ----
    const size_t hbase = ((size_t)wv*NB + b)*NH;
    float r[8];
    #pragma unroll
    for (int j = 0; j < 8; ++j) {
        const int src = h ^ j ^ off;
        r[j] = (src < NH) ? h0[hbase + src] : 0.f;
    }

    const int bpbase = (lane & 48) << 2;     // bpermute base (16-lane group)
    float xc = 0.f, xn = 0.f, yst = 0.f;
    if (wv == 0) xn = x[(size_t)b*TT + h];

    for (int i = 0; i < NI; ++i) {
        if ((unsigned)(i - wv) < (unsigned)NTI) {            // wave-uniform
            const int t0 = (i - wv) * KS;
            const int wr = i & 1, rd = wr ^ 1;

            // ---- phase 1: fetch p[0..15] (partial sums; half1 gets 0 for wv0)
            float p[KS];
            if (wv == 0) {
                xc = xn;
                const int tn = t0 + KS;
                xn = (tn < TT) ? x[(size_t)b*TT + tn + h] : 0.f;
                #pragma unroll
                for (int k = 0; k < KS; ++k) {
                    const float xs = __uint_as_float(__builtin_amdgcn_ds_bpermute(
                        bpbase + (k << 2), __float_as_uint(xc)));
                    p[k] = fmaf(w0s, xs, bias2p);            // 0 in half1 / pad lanes
                }
            } else {
                const float* prow = &pbuf[rd][wv-1][lane][0];
                #pragma unroll
                for (int k = 0; k < KS; ++k) p[k] = prow[k]; // 16x ds_read_b32
            }
            float* pw = &pbuf[wr][wv < NL-1 ? wv : 0][lane][0];

            // ---- phase 2: serial recurrence (registers + DPP + 1 permlane) ----
            float th = 0.f;
            #pragma unroll
            for (int k = 0; k < KS; ++k) {
                float z0 = fmaf(W[0], r[0], p[k]);
                float z1 = fmaf(W[1], r[1], bias2h);
                float z2 = W[2] * r[2];
                float z3 = W[3] * r[3];
                z0 = fmaf(W[4], r[4], z0);
                z1 = fmaf(W[5], r[5], z1);
                z2 = fmaf(W[6], r[6], z2);
                z3 = fmaf(W[7], r[7], z3);
                const float zp = (z0 + z1) + (z2 + z3);      // this half's partial
                const float z  = half_sum(zp);               // full 16-term dot
                const float u  = __builtin_amdgcn_exp2f(z);  // z pre-scaled 2*log2e
                th = fmaf(-2.f, __builtin_amdgcn_rcpf(u + 1.f), 1.f);

                // rebuild r[j] = th[h^j^off]: masked xor8 + 8-op cascade
                r[0] = dpp_xor8_hi(th);
                r[4] = dpp_xor4(r[0]);
                r[1] = dpp_xor1(r[0]);  r[5] = dpp_xor1(r[4]);
                r[2] = dpp_xor2(r[0]);  r[3] = dpp_xor2(r[1]);
                r[6] = dpp_xor2(r[4]);  r[7] = dpp_xor2(r[5]);

                // second tree: consumer projection partial / final linear partial
                float n0 = WN[0] * r[0];
                float n1 = WN[1] * r[1];
                float n2 = WN[2] * r[2];
                float n3 = WN[3] * r[3];
                n0 = fmaf(WN[4], r[4], n0);
                n1 = fmaf(WN[5], r[5], n1);
                n2 = fmaf(WN[6], r[6], n2);
                n3 = fmaf(WN[7], r[7], n3);
                const float np = (n0 + n1) + (n2 + n3);

                if (wv < NL-1) {
                    pw[k] = np;                              // partial; no combine
                } else {
                    const float y = half_sum(np) + blin;     // full y(t0+k)
                    if (h == k) yst = y;
                }
            }

            if (wv == NL-1 && lane < 32)                     // half0: 2b x 16t
                out[(size_t)b*TT + t0 + h] = yst;
            if (t0 + KS == TT && lane < 32 && h < NH)        // final hidden state
                out[(size_t)NB*TT + ((size_t)wv*NB + b)*NH + h] = th;
        }
        __syncthreads();
    }
}

extern "C" void kernel_launch(void* const* d_in, const int* in_sizes, int n_in,
                              void* d_out, int out_size, void* d_ws, size_t ws_size,
                              hipStream_t stream) {
    const float* x         = (const float*)d_in[0];
    const float* h0        = (const float*)d_in[1];
    const float* w_ih0     = (const float*)d_in[2];
    const float* w_ih_rest = (const float*)d_in[3];
    const float* w_hh      = (const float*)d_in[4];
    const float* b_ih      = (const float*)d_in[5];
    const float* b_hh      = (const float*)d_in[6];
    const float* w_lin     = (const float*)d_in[7];
    const float* b_lin     = (const float*)d_in[8];
    float* out = (float*)d_out;

    rnn_pipe<<<dim3(NB / 2), dim3(512), 0, stream>>>(
        x, h0, w_ih0, w_ih_rest, w_hh, b_ih, b_hh, w_lin, b_lin, out);
}

// Round 10
// 809.765 us; speedup vs baseline: 1.0010x; 1.0010x over previous
//
#include <hip/hip_runtime.h>

#define TT 4096
#define NB 512
#define NH 10
#define NL 8
#define KS 16          // timesteps per barrier interval
#define NTI (TT/KS)    // 256 t-intervals per layer
#define NI (NTI + NL - 1)

// ---- DPP lane exchange within each row of 16 lanes (VALU pipe, no LDS) ----
//   row_shr:N -> dst lane i gets src lane i-N ; row_shl:N -> lane i+N
__device__ __forceinline__ float dpp_xor1(float v) {   // quad_perm [1,0,3,2]
    return __int_as_float(__builtin_amdgcn_update_dpp(
        __float_as_int(v), __float_as_int(v), 0xB1, 0xF, 0xF, false));
}
__device__ __forceinline__ float dpp_xor2(float v) {   // quad_perm [2,3,0,1]
    return __int_as_float(__builtin_amdgcn_update_dpp(
        __float_as_int(v), __float_as_int(v), 0x4E, 0xF, 0xF, false));
}
__device__ __forceinline__ float dpp_xor4(float v) {
    // banks 0,2 (h&4==0) need lane h+4 -> row_shl:4 ; banks 1,3 need h-4 -> row_shr:4
    int t = __builtin_amdgcn_update_dpp(
        __float_as_int(v), __float_as_int(v), 0x104, 0xF, 0x5, false); // shl:4
    t = __builtin_amdgcn_update_dpp(
        t, __float_as_int(v), 0x114, 0xF, 0xA, false);                 // shr:4
    return __int_as_float(t);
}
// xor8 applied ONLY to rows 2,3 (lanes 32-63); rows 0,1 keep the old value.
__device__ __forceinline__ float dpp_xor8_hi(float v) {
    return __int_as_float(__builtin_amdgcn_update_dpp(
        __float_as_int(v), __float_as_int(v), 0x128, 0xC, 0xF, false)); // row_ror:8
}
// Sum of the two 32-lane halves, delivered to every lane:
// after swap, (a + b) = lo_partial + hi_partial in all 64 lanes.
__device__ __forceinline__ float half_sum(float z) {
    float a = z, bq = z;
    asm volatile("s_nop 1\n\tv_permlane32_swap_b32 %0, %1"
                 : "+v"(a), "+v"(bq));
    return a + bq;
}

// 8 waves/block (wave = layer), 2 batches/wave, each batch replicated across
// the two 32-lane halves; half m owns terms j in {8m..8m+7} of every 16-dot.
// Grid = 256 blocks -> every CU. Cross-layer handoff: producer writes its
// PARTIAL projection (one b32/step) to a pad-17 slab; the consumer's per-step
// permlane32 combine sums the halves. One barrier per KS steps.
__global__ __launch_bounds__(512, 1)
void rnn_pipe(const float* __restrict__ x, const float* __restrict__ h0,
              const float* __restrict__ w_ih0, const float* __restrict__ w_ih_rest,
              const float* __restrict__ w_hh, const float* __restrict__ b_ih,
              const float* __restrict__ b_hh, const float* __restrict__ w_lin,
              const float* __restrict__ b_lin, float* __restrict__ out)
{
    // [parity][producer_layer][lane][16 k's + pad]
    __shared__ float pbuf[2][NL-1][64][17];            // 60928 B

    const int tid  = threadIdx.x;
    const int wv   = tid >> 6;          // layer index
    const int lane = tid & 63;
    const int half = lane >> 5;         // which 8-term slice of the dots
    const int bg   = (lane >> 4) & 1;   // batch within wave
    const int h    = lane & 15;         // hidden unit (padded 10->16)
    const int b    = blockIdx.x * 2 + bg;
    const int off  = half << 3;

    const float SC = 2.8853900817779268f;   // 2*log2(e), folded into z

    // ---- per-lane weights, pre-permuted: X[j] is the coef of r[j]=th[h^j^off]
    float W[8];     // own recurrence whh (SC-folded)
    float WN[8];    // wv<7: consumer's wih (SC-folded); wv==7: w_lin
    float w0s = 0.f, bias2h = 0.f, bias2p = 0.f;
    const float blin = b_lin[0];

    #pragma unroll
    for (int j = 0; j < 8; ++j) {
        const int src = h ^ j ^ off;
        W[j] = (h < NH && src < NH) ? SC * w_hh[(wv*NH + h)*NH + src] : 0.f;
        if (wv < NL-1)   // layer wv+1's W_ih = w_ih_rest[wv]
            WN[j] = (h < NH && src < NH) ? SC * w_ih_rest[(wv*NH + h)*NH + src] : 0.f;
        else
            WN[j] = (src < NH) ? w_lin[src] : 0.f;
    }
    if (h < NH && half == 0) {          // bias/x terms live in half 0 only
        const float bb = SC * (b_ih[wv*NH + h] + b_hh[wv*NH + h]);
        if (wv == 0) { w0s = SC * w_ih0[h]; bias2p = bb; }
        else bias2h = bb;
    }

    // ---- state init: r[j] = h0 of unit h^j^off ----
    const size_t hbase = ((size_t)wv*NB + b)*NH;
    float r[8];
    #pragma unroll
    for (int j = 0; j < 8; ++j) {
        const int src = h ^ j ^ off;
        r[j] = (src < NH) ? h0[hbase + src] : 0.f;
    }

    const int bpbase = (lane & 48) << 2;     // bpermute base (16-lane group)
    float xc = 0.f, xn = 0.f, yst = 0.f;
    if (wv == 0) xn = x[(size_t)b*TT + h];

    for (int i = 0; i < NI; ++i) {
        if ((unsigned)(i - wv) < (unsigned)NTI) {            // wave-uniform
            const int t0 = (i - wv) * KS;
            const int wr = i & 1, rd = wr ^ 1;

            // ---- phase 1: fetch p[0..15] (partial sums; half1 gets 0 for wv0)
            float p[KS];
            if (wv == 0) {
                xc = xn;
                const int tn = t0 + KS;
                xn = (tn < TT) ? x[(size_t)b*TT + tn + h] : 0.f;
                #pragma unroll
                for (int k = 0; k < KS; ++k) {
                    const float xs = __uint_as_float(__builtin_amdgcn_ds_bpermute(
                        bpbase + (k << 2), __float_as_uint(xc)));
                    p[k] = fmaf(w0s, xs, bias2p);            // 0 in half1 / pad lanes
                }
            } else {
                const float* prow = &pbuf[rd][wv-1][lane][0];
                #pragma unroll
                for (int k = 0; k < KS; ++k) p[k] = prow[k]; // 16x ds_read_b32
            }
            float* pw = &pbuf[wr][wv < NL-1 ? wv : 0][lane][0];

            // ---- phase 2: serial recurrence (registers + DPP + 1 permlane) ----
            float th = 0.f;
            #pragma unroll
            for (int k = 0; k < KS; ++k) {
                float z0 = fmaf(W[0], r[0], p[k]);
                float z1 = fmaf(W[1], r[1], bias2h);
                float z2 = W[2] * r[2];
                float z3 = W[3] * r[3];
                z0 = fmaf(W[4], r[4], z0);
                z1 = fmaf(W[5], r[5], z1);
                z2 = fmaf(W[6], r[6], z2);
                z3 = fmaf(W[7], r[7], z3);
                const float zp = (z0 + z1) + (z2 + z3);      // this half's partial
                const float z  = half_sum(zp);               // full 16-term dot
                const float u  = __builtin_amdgcn_exp2f(z);  // z pre-scaled 2*log2e
                th = fmaf(-2.f, __builtin_amdgcn_rcpf(u + 1.f), 1.f);

                // rebuild r[j] = th[h^j^off]: masked xor8 + 8-op cascade
                r[0] = dpp_xor8_hi(th);
                r[4] = dpp_xor4(r[0]);
                r[1] = dpp_xor1(r[0]);  r[5] = dpp_xor1(r[4]);
                r[2] = dpp_xor2(r[0]);  r[3] = dpp_xor2(r[1]);
                r[6] = dpp_xor2(r[4]);  r[7] = dpp_xor2(r[5]);

                // second tree: consumer projection partial / final linear partial
                float n0 = WN[0] * r[0];
                float n1 = WN[1] * r[1];
                float n2 = WN[2] * r[2];
                float n3 = WN[3] * r[3];
                n0 = fmaf(WN[4], r[4], n0);
                n1 = fmaf(WN[5], r[5], n1);
                n2 = fmaf(WN[6], r[6], n2);
                n3 = fmaf(WN[7], r[7], n3);
                const float np = (n0 + n1) + (n2 + n3);

                if (wv < NL-1) {
                    pw[k] = np;                              // partial; no combine
                } else {
                    const float y = half_sum(np) + blin;     // full y(t0+k)
                    if (h == k) yst = y;
                }
            }

            if (wv == NL-1 && lane < 32)                     // half0: 2b x 16t
                out[(size_t)b*TT + t0 + h] = yst;
            if (t0 + KS == TT && lane < 32 && h < NH)        // final hidden state
                out[(size_t)NB*TT + ((size_t)wv*NB + b)*NH + h] = th;
        }
        __syncthreads();
    }
}

extern "C" void kernel_launch(void* const* d_in, const int* in_sizes, int n_in,
                              void* d_out, int out_size, void* d_ws, size_t ws_size,
                              hipStream_t stream) {
    const float* x         = (const float*)d_in[0];
    const float* h0        = (const float*)d_in[1];
    const float* w_ih0     = (const float*)d_in[2];
    const float* w_ih_rest = (const float*)d_in[3];
    const float* w_hh      = (const float*)d_in[4];
    const float* b_ih      = (const float*)d_in[5];
    const float* b_hh      = (const float*)d_in[6];
    const float* w_lin     = (const float*)d_in[7];
    const float* b_lin     = (const float*)d_in[8];
    float* out = (float*)d_out;

    rnn_pipe<<<dim3(NB / 2), dim3(512), 0, stream>>>(
        x, h0, w_ih0, w_ih_rest, w_hh, b_ih, b_hh, w_lin, b_lin, out);
}